// Round 8
// baseline (17.179 us; speedup 1.0000x reference)
//
#include <hip/hip_runtime.h>

// y[b,f,d] = relu( prefixW[d, fi] + frac * W[d, fi] + bias[d] ),
//   fi = floor(x+1000), frac = (x+1000) - fi.   B=128, F=512, D=128, NB=2000.
//
// Packed bf16 table, TILED layout:
//   T[tile][n][dw]  (tile = d>>4, dw = d&15),  u32 = { bf16(Wt)<<16 | bf16(Ct) }
//   Ct = sum_{k<n} W[d,k] + bias[d]  (bias folded),  Wt = W[d,n].
//   Row NB=2000 holds the full sum (pos==2000.0 float-rounding edge), Wt=0.
// 64B line = 16 adjacent d's of one row n; build blocks swizzled
// (d = (bid&7)*16 + (bid>>3)) so a tile's 16 column-writers share an XCD.
// Build stores are NONTEMPORAL: write-through so eval's first-touch gathers
// are clean L3 fills instead of cross-XCD dirty-L2 probes.
//
// K1 build: 128 blocks x 256 thr; thread c sums its 8-bin chunk, block scan
//           (wave shfl + LDS wave totals), emits packed entries (NT stores).
// K2 eval : 2048 blocks x 256 thr, 32 pairs/block; per pair one 16B gather
//           per lane (4 lanes/64B line); nontemporal f4 out stores.

#define NB    2000
#define DD    128
#define CHUNK 8
#define CH    250            // CH*CHUNK == NB
#define NPAIR (128 * 512)
#define TROW  (NB + 1)       // rows per tile
#define PPB   32             // pairs per eval block

typedef float f4 __attribute__((ext_vector_type(4)));
typedef unsigned int u32;
typedef u32 u4 __attribute__((ext_vector_type(4)));

__device__ __forceinline__ u32 pack_bf16(float ct, float wt) {
    u32 cb = (__float_as_uint(ct) + 0x8000u) >> 16;          // RN bf16, low
    u32 wb = (__float_as_uint(wt) + 0x8000u) & 0xffff0000u;  // RN bf16, high
    return wb | cb;
}

// ---------------------------------------------------------------------------
__global__ __launch_bounds__(256) void build_kernel(const float* __restrict__ W,
                                                    const float* __restrict__ bias,
                                                    u32* __restrict__ T) {
    const int bid = blockIdx.x;            // 0..127
    const int d   = (bid & 7) * 16 + (bid >> 3);   // XCD-coherent tile mapping
    const int t   = threadIdx.x;           // chunk id; 0..249 active

    f4 a = {0.f, 0.f, 0.f, 0.f}, b = {0.f, 0.f, 0.f, 0.f};
    float s = 0.f;
    if (t < CH) {
        const f4* p = (const f4*)(W + (size_t)d * NB + t * CHUNK);
        a = p[0]; b = p[1];
        s = ((a.x + a.y) + (a.z + a.w)) + ((b.x + b.y) + (b.z + b.w));
    }

    // wave-level inclusive scan
    float inc = s;
    #pragma unroll
    for (int off = 1; off < 64; off <<= 1) {
        float o = __shfl_up(inc, off);
        if ((t & 63) >= off) inc += o;
    }
    // block-level: totals of preceding waves
    __shared__ float wtot[4];
    const int w = t >> 6, l = t & 63;
    if (l == 63) wtot[w] = inc;
    __syncthreads();
    float add = 0.f;
    #pragma unroll
    for (int k = 0; k < 3; k++)
        if (k < w) add += wtot[k];

    if (t < CH) {
        float run = (inc - s) + add + bias[d];
        const float wv[CHUNK] = {a.x, a.y, a.z, a.w, b.x, b.y, b.z, b.w};
        // tiled destination: T[d>>4][n][d&15]
        u32* col = T + (size_t)(d >> 4) * TROW * 16 + (d & 15);
        const int nbase = t * CHUNK;
        #pragma unroll
        for (int i = 0; i < CHUNK; i++) {
            __builtin_nontemporal_store(pack_bf16(run, wv[i]),
                                        col + (size_t)(nbase + i) * 16);
            run += wv[i];
        }
        if (t == CH - 1) {          // row NB: full prefix (rounding edge)
            __builtin_nontemporal_store(pack_bf16(run, 0.f),
                                        col + (size_t)NB * 16);
        }
    }
}

// ---------------------------------------------------------------------------
__global__ __launch_bounds__(256) void eval_kernel(const float* __restrict__ x,
                                                   const u4* __restrict__ T4,
                                                   float* __restrict__ out) {
    const int tid  = threadIdx.x;
    const int lane = tid & 31;      // 32 lanes x 4 d's cover d=0..127
    const int slot = tid >> 5;      // 0..7
    const int base = blockIdx.x * PPB;
    // lane's tile and within-line quad: d4 = lane*4
    const int tile = lane >> 2;             // d4 >> 4
    const int quad = lane & 3;              // (d4 & 15) / 4
    const int tbase = tile * (TROW * 4) + quad;   // u4 units

    #pragma unroll
    for (int h = 0; h < PPB / 8; h++) {
        const int pair = base + slot + h * 8;
        const float pos = x[pair] + 1000.0f;
        const float fl  = floorf(pos);
        float frac = pos - fl;
        int fi = (int)fl;
        if (fi >= NB) { fi = NB; frac = 0.f; }
        if (fi < 0)   { fi = 0;  frac = 0.f; }

        // one 16B gather: 4 packed entries = d4..d4+3 of row fi in this tile
        const u4 q = T4[tbase + fi * 4];

        f4 r;
        {
            float ct0 = __uint_as_float(q.x << 16);
            float wt0 = __uint_as_float(q.x & 0xffff0000u);
            float ct1 = __uint_as_float(q.y << 16);
            float wt1 = __uint_as_float(q.y & 0xffff0000u);
            float ct2 = __uint_as_float(q.z << 16);
            float wt2 = __uint_as_float(q.z & 0xffff0000u);
            float ct3 = __uint_as_float(q.w << 16);
            float wt3 = __uint_as_float(q.w & 0xffff0000u);
            r.x = fmaxf(fmaf(frac, wt0, ct0), 0.f);
            r.y = fmaxf(fmaf(frac, wt1, ct1), 0.f);
            r.z = fmaxf(fmaf(frac, wt2, ct2), 0.f);
            r.w = fmaxf(fmaf(frac, wt3, ct3), 0.f);
        }

        __builtin_nontemporal_store(r, (f4*)(out + (size_t)pair * DD + lane * 4));
    }
}

extern "C" void kernel_launch(void* const* d_in, const int* in_sizes, int n_in,
                              void* d_out, int out_size, void* d_ws, size_t ws_size,
                              hipStream_t stream) {
    const float* x    = (const float*)d_in[0];   // [128, 512]
    const float* W    = (const float*)d_in[1];   // [128, 2000]
    const float* bias = (const float*)d_in[2];   // [128]
    float* out = (float*)d_out;                  // [128, 512, 128] f32

    u32* T = (u32*)d_ws;                         // 8 tiles x 2001 x 16 u32 ~1.02MB

    hipLaunchKernelGGL(build_kernel, dim3(DD), dim3(256), 0, stream, W, bias, T);
    hipLaunchKernelGGL(eval_kernel, dim3(NPAIR / PPB), dim3(256), 0, stream,
                       x, (const u4*)T, out);
}

// Round 9
// 16.609 us; speedup vs baseline: 1.0343x; 1.0343x over previous
//
#include <hip/hip_runtime.h>

// y[b,f,d] = relu( prefixW[d, fi] + frac * W[d, fi] + bias[d] ),
//   fi = floor(x+1000), frac = (x+1000) - fi.   B=128, F=512, D=128, NB=2000.
//
// Packed bf16 table, TILED layout:
//   T[tile][n][dw]  (tile = d>>4, dw = d&15),  u32 = { bf16(Wt)<<16 | bf16(Ct) }
//   Ct = sum_{k<n} W[d,k] + bias[d]  (bias folded),  Wt = W[d,n].
//   Row NB=2000 holds the full sum (pos==2000.0 float-rounding edge), Wt=0.
// 64B line = 16 adjacent d's of one row n; build blocks swizzled
// (d = (bid&7)*16 + (bid>>3)) so a tile's 16 column-writers share an XCD ->
// their 4B stores merge into full dirty lines in that XCD's L2 (regular,
// L2-allocating stores — NT stores here measurably regress: R8).
//
// K1 build: 128 blocks x 256 thr; thread c sums its 8-bin chunk, block scan
//           (wave shfl + LDS wave totals), emits packed entries.
// K2 eval : 4096 blocks x 256 thr, 16 pairs/block; per pair one 16B gather
//           per lane (4 lanes/64B line); nontemporal f4 out stores.

#define NB    2000
#define DD    128
#define CHUNK 8
#define CH    250            // CH*CHUNK == NB
#define NPAIR (128 * 512)
#define TROW  (NB + 1)       // rows per tile

typedef float f4 __attribute__((ext_vector_type(4)));
typedef unsigned int u32;
typedef u32 u4 __attribute__((ext_vector_type(4)));

__device__ __forceinline__ u32 pack_bf16(float ct, float wt) {
    u32 cb = (__float_as_uint(ct) + 0x8000u) >> 16;          // RN bf16, low
    u32 wb = (__float_as_uint(wt) + 0x8000u) & 0xffff0000u;  // RN bf16, high
    return wb | cb;
}

// ---------------------------------------------------------------------------
__global__ __launch_bounds__(256) void build_kernel(const float* __restrict__ W,
                                                    const float* __restrict__ bias,
                                                    u32* __restrict__ T) {
    const int bid = blockIdx.x;            // 0..127
    const int d   = (bid & 7) * 16 + (bid >> 3);   // XCD-coherent tile mapping
    const int t   = threadIdx.x;           // chunk id; 0..249 active

    f4 a = {0.f, 0.f, 0.f, 0.f}, b = {0.f, 0.f, 0.f, 0.f};
    float s = 0.f;
    if (t < CH) {
        const f4* p = (const f4*)(W + (size_t)d * NB + t * CHUNK);
        a = p[0]; b = p[1];
        s = ((a.x + a.y) + (a.z + a.w)) + ((b.x + b.y) + (b.z + b.w));
    }

    // wave-level inclusive scan
    float inc = s;
    #pragma unroll
    for (int off = 1; off < 64; off <<= 1) {
        float o = __shfl_up(inc, off);
        if ((t & 63) >= off) inc += o;
    }
    // block-level: totals of preceding waves
    __shared__ float wtot[4];
    const int w = t >> 6, l = t & 63;
    if (l == 63) wtot[w] = inc;
    __syncthreads();
    float add = 0.f;
    #pragma unroll
    for (int k = 0; k < 3; k++)
        if (k < w) add += wtot[k];

    if (t < CH) {
        float run = (inc - s) + add + bias[d];
        const float wv[CHUNK] = {a.x, a.y, a.z, a.w, b.x, b.y, b.z, b.w};
        // tiled destination: T[d>>4][n][d&15]
        u32* col = T + (size_t)(d >> 4) * TROW * 16 + (d & 15);
        const int nbase = t * CHUNK;
        #pragma unroll
        for (int i = 0; i < CHUNK; i++) {
            col[(size_t)(nbase + i) * 16] = pack_bf16(run, wv[i]);
            run += wv[i];
        }
        if (t == CH - 1) {          // row NB: full prefix (rounding edge)
            col[(size_t)NB * 16] = pack_bf16(run, 0.f);
        }
    }
}

// ---------------------------------------------------------------------------
__global__ __launch_bounds__(256) void eval_kernel(const float* __restrict__ x,
                                                   const u4* __restrict__ T4,
                                                   float* __restrict__ out) {
    const int tid  = threadIdx.x;
    const int lane = tid & 31;      // 32 lanes x 4 d's cover d=0..127
    const int slot = tid >> 5;      // 0..7
    const int base = blockIdx.x * 16;
    // lane's tile and within-line quad: d4 = lane*4
    const int tile = lane >> 2;             // d4 >> 4
    const int quad = lane & 3;              // (d4 & 15) / 4
    const int tbase = tile * (TROW * 4) + quad;   // u4 units

    #pragma unroll
    for (int h = 0; h < 2; h++) {
        const int pair = base + slot + h * 8;
        const float pos = x[pair] + 1000.0f;
        const float fl  = floorf(pos);
        float frac = pos - fl;
        int fi = (int)fl;
        if (fi >= NB) { fi = NB; frac = 0.f; }
        if (fi < 0)   { fi = 0;  frac = 0.f; }

        // one 16B gather: 4 packed entries = d4..d4+3 of row fi in this tile
        const u4 q = T4[tbase + fi * 4];

        f4 r;
        {
            float ct0 = __uint_as_float(q.x << 16);
            float wt0 = __uint_as_float(q.x & 0xffff0000u);
            float ct1 = __uint_as_float(q.y << 16);
            float wt1 = __uint_as_float(q.y & 0xffff0000u);
            float ct2 = __uint_as_float(q.z << 16);
            float wt2 = __uint_as_float(q.z & 0xffff0000u);
            float ct3 = __uint_as_float(q.w << 16);
            float wt3 = __uint_as_float(q.w & 0xffff0000u);
            r.x = fmaxf(fmaf(frac, wt0, ct0), 0.f);
            r.y = fmaxf(fmaf(frac, wt1, ct1), 0.f);
            r.z = fmaxf(fmaf(frac, wt2, ct2), 0.f);
            r.w = fmaxf(fmaf(frac, wt3, ct3), 0.f);
        }

        __builtin_nontemporal_store(r, (f4*)(out + (size_t)pair * DD + lane * 4));
    }
}

extern "C" void kernel_launch(void* const* d_in, const int* in_sizes, int n_in,
                              void* d_out, int out_size, void* d_ws, size_t ws_size,
                              hipStream_t stream) {
    const float* x    = (const float*)d_in[0];   // [128, 512]
    const float* W    = (const float*)d_in[1];   // [128, 2000]
    const float* bias = (const float*)d_in[2];   // [128]
    float* out = (float*)d_out;                  // [128, 512, 128] f32

    u32* T = (u32*)d_ws;                         // 8 tiles x 2001 x 16 u32 ~1.02MB

    hipLaunchKernelGGL(build_kernel, dim3(DD), dim3(256), 0, stream, W, bias, T);
    hipLaunchKernelGGL(eval_kernel, dim3(NPAIR / 16), dim3(256), 0, stream,
                       x, (const u4*)T, out);
}